// Round 3
// baseline (243.597 us; speedup 1.0000x reference)
//
#include <hip/hip_runtime.h>

// SSIM (win=7, valid) fused single-pass kernel for (32,3,512,512) fp32 inputs.
// 96 images of 512x512 -> mean over 96x506x506 S map.
//
// R3: barrier-free inner loop. Each block = 5 waves; each wave owns a disjoint
// 122-output-col segment (122*5=610>=506) and loads its own 128 input cols
// (64 lanes x 2). Horizontal 7-sum via wave-internal __shfl_down (no LDS, no
// __syncthreads in the loop) so global prefetch loads stay in flight across
// the whole row body. /49 normalization folded algebraically (2401 cancels in
// the S ratio); v_rcp_f32 replaces IEEE div.

namespace {
constexpr int W      = 512;
constexpr int HH     = 512;
constexpr int NIMG   = 96;
constexpr int OW     = 506;
constexpr int RSTRIP = 23;   // 22 * 23 = 506 output rows exactly
constexpr int NSTRIP = 22;
constexpr int SEGW   = 122;  // output cols per wave (inputs: 128 = 64 lanes x 2)
// S = (2 ux uy + C1)(2 vxy + C2) / ((ux^2+uy^2+C1)(vx+vy+C2)); with U = 49*u
// sums, every term carries 1/2401 which cancels in the ratio:
constexpr float D1      = 0.2401f;                  // C1 * 49^2
constexpr float D2      = 2.1609f;                  // C2 * 49^2
constexpr float COVN    = 49.0f / 48.0f;            // NP/(NP-1)
constexpr float COV2    = 2.0f * COVN;              // 49/24
constexpr float K49COV  = 49.0f * COVN;             // 2401/48
constexpr float K49COV2 = 2.0f * 49.0f * COVN;      // 4802/48
constexpr double NPIX   = 96.0 * 506.0 * 506.0;     // 24,579,456
}

__global__ __launch_bounds__(320, 6) void ssim_main(const float* __restrict__ X,
                                                    const float* __restrict__ Y,
                                                    double* __restrict__ acc)
{
    __shared__ float wsum[5];

    const int t    = threadIdx.x;
    const int wave = t >> 6;          // 0..4 : column segment
    const int lane = t & 63;
    const int img  = blockIdx.y;
    const int r0   = blockIdx.x * RSTRIP;      // first output row of strip

    const int s  = wave * SEGW;                // segment's first output col
    const int lc = 2 * lane;                   // local col pair within segment
    int g = s + lc; if (g > W - 2) g = W - 2;  // clamped global col (float2-safe)

    const float* xb = X + (size_t)img * W * HH + g;
    const float* yb = Y + (size_t)img * W * HH + g;

    // validity of this lane's two output pixels (lanes 61-63 & OOB cols masked)
    const bool ok0 = (lc     < SEGW) && (s + lc     < OW);
    const bool ok1 = (lc + 1 < SEGW) && (s + lc + 1 < OW);

    // running vertical sums over the 7-row window, per column:
    // V[0]=sum x, V[1]=sum y, V[2]=sum x^2, V[3]=sum y^2, V[4]=sum x*y
    float V[5][2];
#pragma unroll
    for (int q = 0; q < 5; q++)
#pragma unroll
        for (int i = 0; i < 2; i++) V[q][i] = 0.0f;

    // warm-up: rows r0 .. r0+5
#pragma unroll
    for (int k = 0; k < 6; k++) {
        float2 x2 = *(const float2*)(xb + (size_t)(r0 + k) * W);
        float2 y2 = *(const float2*)(yb + (size_t)(r0 + k) * W);
        float xs[2] = {x2.x, x2.y};
        float ys[2] = {y2.x, y2.y};
#pragma unroll
        for (int i = 0; i < 2; i++) {
            V[0][i] += xs[i];
            V[1][i] += ys[i];
            V[2][i] = fmaf(xs[i], xs[i], V[2][i]);
            V[3][i] = fmaf(ys[i], ys[i], V[3][i]);
            V[4][i] = fmaf(xs[i], ys[i], V[4][i]);
        }
    }

    // first bottom row of the window
    float2 xn = *(const float2*)(xb + (size_t)(r0 + 6) * W);
    float2 yn = *(const float2*)(yb + (size_t)(r0 + 6) * W);

    float sacc = 0.0f;

    for (int j = 0; j < RSTRIP; j++) {
        // add bottom row (r0 + j + 6)
        {
            float xs[2] = {xn.x, xn.y};
            float ys[2] = {yn.x, yn.y};
#pragma unroll
            for (int i = 0; i < 2; i++) {
                V[0][i] += xs[i];
                V[1][i] += ys[i];
                V[2][i] = fmaf(xs[i], xs[i], V[2][i]);
                V[3][i] = fmaf(ys[i], ys[i], V[3][i]);
                V[4][i] = fmaf(xs[i], ys[i], V[4][i]);
            }
        }

        // prefetch: old top row (subtract later) and next bottom row.
        // No barrier anywhere below -> these stay in flight until first use.
        float2 xo  = *(const float2*)(xb + (size_t)(r0 + j) * W);
        float2 yo  = *(const float2*)(yb + (size_t)(r0 + j) * W);
        int rn = r0 + j + 7; if (rn > HH - 1) rn = HH - 1;   // clamped; unused on last iter
        float2 xn2 = *(const float2*)(xb + (size_t)rn * W);
        float2 yn2 = *(const float2*)(yb + (size_t)rn * W);

        // horizontal 7-sums via wave-internal shuffles (cols 2l..2l+6 / 2l+1..2l+7)
        float Hs[5][2];
#pragma unroll
        for (int q = 0; q < 5; q++) {
            float v0 = V[q][0], v1 = V[q][1];
            float P  = v0 + v1;                 // pair sum (2l, 2l+1)
            float P1 = __shfl_down(P,  1);      // (2l+2, 2l+3)
            float P2 = __shfl_down(P,  2);      // (2l+4, 2l+5)
            float P3 = __shfl_down(P,  3);      // (2l+6, 2l+7)
            float a3 = __shfl_down(v0, 3);      // 2l+6
            Hs[q][0] = (P  + P1) + (P2 + a3);
            Hs[q][1] = (v1 + P1) + (P2 + P3);
        }

        // SSIM per output pixel (U = 49*u; common 1/2401 factors cancel)
#pragma unroll
        for (int i = 0; i < 2; i++) {
            float U0 = Hs[0][i], U1 = Hs[1][i];
            float U2 = Hs[2][i], U3 = Hs[3][i], U4 = Hs[4][i];
            float A    = U0 * U1;
            float q01  = fmaf(U0, U0, U1 * U1);
            float num1 = fmaf(2.0f, A, D1);
            float den1 = q01 + D1;
            float num2 = fmaf(K49COV2, U4, fmaf(-COV2, A, D2));
            float s23  = U2 + U3;
            float den2 = fmaf(K49COV, s23, fmaf(-COVN, q01, D2));
            float S = (num1 * num2) * __builtin_amdgcn_rcpf(den1 * den2);
            bool ok = i ? ok1 : ok0;
            sacc += ok ? S : 0.0f;
        }

        // subtract top row (r0 + j)
        {
            float xs[2] = {xo.x, xo.y};
            float ys[2] = {yo.x, yo.y};
#pragma unroll
            for (int i = 0; i < 2; i++) {
                V[0][i] -= xs[i];
                V[1][i] -= ys[i];
                V[2][i] = fmaf(-xs[i], xs[i], V[2][i]);
                V[3][i] = fmaf(-ys[i], ys[i], V[3][i]);
                V[4][i] = fmaf(-xs[i], ys[i], V[4][i]);
            }
        }
        xn = xn2; yn = yn2;
    }

    // reduction: wave shuffle -> LDS (one barrier, after the loop) -> 1 atomic
#pragma unroll
    for (int off = 32; off > 0; off >>= 1)
        sacc += __shfl_down(sacc, off);
    if (lane == 0) wsum[wave] = sacc;
    __syncthreads();
    if (t == 0) {
        float b = ((wsum[0] + wsum[1]) + (wsum[2] + wsum[3])) + wsum[4];
        atomicAdd(acc, (double)b);
    }
}

__global__ void ssim_finalize(const double* __restrict__ acc, float* __restrict__ out)
{
    out[0] = (float)(acc[0] / NPIX);
}

extern "C" void kernel_launch(void* const* d_in, const int* in_sizes, int n_in,
                              void* d_out, int out_size, void* d_ws, size_t ws_size,
                              hipStream_t stream)
{
    const float* X = (const float*)d_in[0];   // input_tensor (32,3,512,512) fp32
    const float* Y = (const float*)d_in[1];   // target       (32,3,512,512) fp32
    float* out = (float*)d_out;               // scalar fp32
    double* acc = (double*)d_ws;

    hipMemsetAsync(d_ws, 0, sizeof(double), stream);
    ssim_main<<<dim3(NSTRIP, NIMG), 320, 0, stream>>>(X, Y, acc);
    ssim_finalize<<<1, 1, 0, stream>>>(acc, out);
}